// Round 5
// baseline (247.327 us; speedup 1.0000x reference)
//
#include <hip/hip_runtime.h>

#define B_ 4
#define W_ 2048
#define C_ 1024
#define NH 16
#define KH 64

typedef __attribute__((ext_vector_type(8))) short short8;
typedef __attribute__((ext_vector_type(4))) short s16x4;
typedef __attribute__((ext_vector_type(4))) float f32x4;

__device__ __forceinline__ short f2bf(float f) {
    unsigned u = __builtin_bit_cast(unsigned, f);
    u = (u + 0x7FFFu + ((u >> 16) & 1u)) >> 16;
    return (short)u;
}
__device__ __forceinline__ float bf2f(short h) {
    return __builtin_bit_cast(float, ((unsigned)(unsigned short)h) << 16);
}

#define MFMA(a, b, cc) __builtin_amdgcn_mfma_f32_16x16x32_bf16(a, b, cc, 0, 0, 0)

// ---------------- metric[n] = P[n] @ P[n]^T ----------------
__global__ __launch_bounds__(256) void k_metric(const float* __restrict__ P, float* __restrict__ M) {
    int n = blockIdx.x;
    __shared__ float sP[KH * KH];
    __shared__ float sPt[KH * 65];
    const float* Pn = P + n * KH * KH;
    for (int i = threadIdx.x; i < KH * KH; i += 256) {
        float v = Pn[i];
        sP[i] = v;
        sPt[(i & 63) * 65 + (i >> 6)] = v;
    }
    __syncthreads();
    float* Mn = M + n * KH * KH;
    for (int e = threadIdx.x; e < KH * KH; e += 256) {
        int i = e >> 6, k = e & 63;
        float s = 0.f;
        #pragma unroll 8
        for (int j = 0; j < KH; ++j) s += sP[i * KH + j] * sPt[j * 65 + k];
        Mn[e] = s;
    }
}

// ---------------- Wq[n*64+jj][c] = 0.125 * sum_k M[n][k][jj] * Wp[n*64+k][c] ----------------
__global__ __launch_bounds__(256) void k_wq(const float* __restrict__ M, const float* __restrict__ Wp,
                                            short* __restrict__ Wq) {
    int n = blockIdx.y, cseg = blockIdx.x;
    __shared__ float sM[KH * KH];
    __shared__ float sW[KH * KH];
    for (int i = threadIdx.x; i < KH * KH; i += 256) {
        sM[i] = M[n * KH * KH + i];
        int r = i >> 6, c = i & 63;
        sW[i] = Wp[(n * KH + r) * C_ + cseg * KH + c];
    }
    __syncthreads();
    for (int e = threadIdx.x; e < KH * KH; e += 256) {
        int jj = e >> 6, c = e & 63;
        float s = 0.f;
        #pragma unroll 8
        for (int k = 0; k < KH; ++k) s += sM[k * KH + jj] * sW[k * KH + c];
        Wq[(n * KH + jj) * C_ + cseg * KH + c] = f2bf(s * 0.125f);   // fold 1/sqrt(K)
    }
}

// ---------------- Wf[o][n*64+k] = sum_j T[n][k][j] * Wm[o][n*64+j] ----------------
__global__ __launch_bounds__(256) void k_wf(const float* __restrict__ T, const float* __restrict__ Wm,
                                            short* __restrict__ Wf) {
    int n = blockIdx.y, oseg = blockIdx.x;
    __shared__ float sTt[KH * 65];
    __shared__ float sW[KH * KH];
    for (int i = threadIdx.x; i < KH * KH; i += 256) {
        sTt[(i & 63) * 65 + (i >> 6)] = T[n * KH * KH + i];
        int r = i >> 6, c = i & 63;
        sW[i] = Wm[(oseg * KH + r) * C_ + n * KH + c];
    }
    __syncthreads();
    for (int e = threadIdx.x; e < KH * KH; e += 256) {
        int r = e >> 6, k = e & 63;
        float s = 0.f;
        #pragma unroll 8
        for (int j = 0; j < KH; ++j) s += sTt[j * 65 + k] * sW[r * KH + j];
        Wf[(oseg * KH + r) * C_ + n * KH + k] = f2bf(s);
    }
}

// ---------------- fp32 -> bf16 convert ----------------
__global__ __launch_bounds__(256) void k_cvt(const float* __restrict__ src, short* __restrict__ dst, int n4) {
    int i = blockIdx.x * 256 + threadIdx.x;
    if (i < n4) {
        float4 v = ((const float4*)src)[i];
        short4 o;
        o.x = f2bf(v.x); o.y = f2bf(v.y); o.z = f2bf(v.z); o.w = f2bf(v.w);
        ((short4*)dst)[i] = o;
    }
}

// ---------------- 256x256-tile 8-phase GEMM, balanced read-ahead schedule ----------------
// 8 waves (2M x 4N), BK=64, LDS = 2dbuf x 2half x {A,B} x 16KB = 128KB.
// Reads feed the NEXT phase's MFMA (register read-ahead), 6 ds_read_b128 per phase.
// ROUND-5 FIX: waitcnt asms must have NO "memory" clobber (a memory clobber makes the
// waitcnt-insertion pass treat the asm as may-load/store and flush vmcnt/lgkmcnt to 0 —
// turning the counted waits into full drains = the m97 barrier-drain stall). Ordering
// safety: every drained buffer is only read AFTER the subsequent s_barrier. A
// sched_barrier(0) after each waitcnt pins MFMA clusters from drifting across (rule #18).
template <int OC>
__global__ __launch_bounds__(512, 2) void k_gemm256(const short* __restrict__ A, const short* __restrict__ Bw,
                                                    short* __restrict__ Out) {
    constexpr int NBX = OC / 256;
    constexpr int NT = C_ / 64;          // 16 K-tiles
    __shared__ short As[4 * 8192];       // [dbuf][half][128 rows][64]
    __shared__ short Bs[4 * 8192];
    int tid = threadIdx.x;
    int wave = tid >> 6, lane = tid & 63;
    int q = lane >> 4, c = lane & 15;
    int wm = wave >> 2, wn = wave & 3;
    // T1: bijective XCD swizzle (grid = NBX*32 blocks, %8 == 0)
    int id = blockIdx.x + blockIdx.y * NBX;
    int f = (id & 7) * (NBX * 32 / 8) + (id >> 3);
    int bm = f / NBX, bn = f % NBX;
    int A_B0 = bm * 256, Bw_B0 = bn * 256;

    // staging geometry: 2 x global_load_lds per thread per half-tile
    int r0 = tid >> 3, sub0 = tid & 7;
    int r1 = r0 + 64;
    int sc0 = (sub0 ^ (r0 & 7)) * 8;     // pre-swizzled global k-chunk
    int sc1 = (sub0 ^ (r1 & 7)) * 8;
    int dst0 = wave * 512;
    int dst1 = 4096 + dst0;

#define STAGE(BUF, MAT, T, H)                                                                    \
    {                                                                                            \
        int _reg = (((T) & 1) * 2 + (H)) * 8192;                                                 \
        const short* _s = &MAT[(size_t)(MAT##_B0 + (H) * 128) * 1024 + (T) * 64];                \
        __builtin_amdgcn_global_load_lds(                                                        \
            (const __attribute__((address_space(1))) void*)&_s[(size_t)r0 * 1024 + sc0],         \
            (__attribute__((address_space(3))) void*)&BUF[_reg + dst0], 16, 0, 0);               \
        __builtin_amdgcn_global_load_lds(                                                        \
            (const __attribute__((address_space(1))) void*)&_s[(size_t)r1 * 1024 + sc1],         \
            (__attribute__((address_space(3))) void*)&BUF[_reg + dst1], 16, 0, 0);               \
    }

    int arow = (wm * 64 + c) * 64;
    int brow = (wn * 32 + c) * 64;
    int xk0 = ((0 + q) ^ (c & 7)) * 8;
    int xk1 = ((4 + q) ^ (c & 7)) * 8;

    f32x4 acc[2][2][4][2] = {};
    short8 af0[4][2], af1[4][2], bf0[2][2], bf1[2][2], bf0n[2][2];

    // prologue: tile0 full, then tile1 full
    STAGE(As, A, 0, 0) STAGE(Bs, Bw, 0, 0) STAGE(As, A, 0, 1) STAGE(Bs, Bw, 0, 1)
    STAGE(As, A, 1, 0) STAGE(Bs, Bw, 1, 0) STAGE(As, A, 1, 1) STAGE(Bs, Bw, 1, 1)
    asm volatile("s_waitcnt vmcnt(8)");   // tile0 drained; tile1's 8 loads in flight
    __builtin_amdgcn_sched_barrier(0);
    __builtin_amdgcn_s_barrier();
    // register preload: tile0 A-h0 frags + B-h0 frags ("P3/P4 of g=-1")
    #pragma unroll
    for (int i = 0; i < 4; ++i) {
        af0[i][0] = *(const short8*)&As[arow + i * 1024 + xk0];
        af0[i][1] = *(const short8*)&As[arow + i * 1024 + xk1];
    }
    #pragma unroll
    for (int j = 0; j < 2; ++j) {
        bf0[j][0] = *(const short8*)&Bs[brow + j * 1024 + xk0];
        bf0[j][1] = *(const short8*)&Bs[brow + j * 1024 + xk1];
    }

    for (int g = 0; g < NT; ++g) {
        int X = (g & 1) * 16384;
        int X1 = X ^ 16384;
        // ---- P1: MFMA(0,0); read bf1(4)+af1[0](2); stage A(g+2,h0) ----
        if (g + 2 < NT) STAGE(As, A, g + 2, 0);
        #pragma unroll
        for (int j = 0; j < 2; ++j) {
            bf1[j][0] = *(const short8*)&Bs[X + 8192 + brow + j * 1024 + xk0];
            bf1[j][1] = *(const short8*)&Bs[X + 8192 + brow + j * 1024 + xk1];
        }
        af1[0][0] = *(const short8*)&As[X + 8192 + arow + xk0];
        af1[0][1] = *(const short8*)&As[X + 8192 + arow + xk1];
        __builtin_amdgcn_s_barrier();
        __builtin_amdgcn_s_setprio(1);
        #pragma unroll
        for (int i = 0; i < 4; ++i)
            #pragma unroll
            for (int j = 0; j < 2; ++j) {
                acc[0][0][i][j] = MFMA(af0[i][0], bf0[j][0], acc[0][0][i][j]);
                acc[0][0][i][j] = MFMA(af0[i][1], bf0[j][1], acc[0][0][i][j]);
            }
        __builtin_amdgcn_s_setprio(0);
        __builtin_amdgcn_s_barrier();
        // ---- P2: MFMA(0,1); read af1[1..3](6); stage B(g+2,h1); vmcnt ----
        if (g + 2 < NT) STAGE(Bs, Bw, g + 2, 1);
        #pragma unroll
        for (int i = 1; i < 4; ++i) {
            af1[i][0] = *(const short8*)&As[X + 8192 + arow + i * 1024 + xk0];
            af1[i][1] = *(const short8*)&As[X + 8192 + arow + i * 1024 + xk1];
        }
        __builtin_amdgcn_s_barrier();
        __builtin_amdgcn_s_setprio(1);
        #pragma unroll
        for (int i = 0; i < 4; ++i)
            #pragma unroll
            for (int j = 0; j < 2; ++j) {
                acc[0][1][i][j] = MFMA(af0[i][0], bf1[j][0], acc[0][1][i][j]);
                acc[0][1][i][j] = MFMA(af0[i][1], bf1[j][1], acc[0][1][i][j]);
            }
        __builtin_amdgcn_s_setprio(0);
        if (g < NT - 2)       { asm volatile("s_waitcnt vmcnt(10)"); }
        else if (g == NT - 2) { asm volatile("s_waitcnt vmcnt(6)"); }
        __builtin_amdgcn_sched_barrier(0);
        __builtin_amdgcn_s_barrier();
        // ---- P3: MFMA(1,1); read next-tile af0[0..2](6); stage A(g+2,h1); vmcnt ----
        if (g + 2 < NT) STAGE(As, A, g + 2, 1);
        if (g + 1 < NT) {
            #pragma unroll
            for (int i = 0; i < 3; ++i) {
                af0[i][0] = *(const short8*)&As[X1 + arow + i * 1024 + xk0];
                af0[i][1] = *(const short8*)&As[X1 + arow + i * 1024 + xk1];
            }
        }
        __builtin_amdgcn_s_barrier();
        __builtin_amdgcn_s_setprio(1);
        #pragma unroll
        for (int i = 0; i < 4; ++i)
            #pragma unroll
            for (int j = 0; j < 2; ++j) {
                acc[1][1][i][j] = MFMA(af1[i][0], bf1[j][0], acc[1][1][i][j]);
                acc[1][1][i][j] = MFMA(af1[i][1], bf1[j][1], acc[1][1][i][j]);
            }
        __builtin_amdgcn_s_setprio(0);
        if (g < NT - 2)       { asm volatile("s_waitcnt vmcnt(6)"); }
        else if (g == NT - 2) { asm volatile("s_waitcnt vmcnt(0)"); }
        __builtin_amdgcn_sched_barrier(0);
        __builtin_amdgcn_s_barrier();
        // ---- P4: MFMA(1,0); read next-tile af0[3](2)+bf0n(4); stage B(g+2,h0) ----
        if (g + 2 < NT) STAGE(Bs, Bw, g + 2, 0);
        if (g + 1 < NT) {
            af0[3][0] = *(const short8*)&As[X1 + arow + 3 * 1024 + xk0];
            af0[3][1] = *(const short8*)&As[X1 + arow + 3 * 1024 + xk1];
            #pragma unroll
            for (int j = 0; j < 2; ++j) {
                bf0n[j][0] = *(const short8*)&Bs[X1 + brow + j * 1024 + xk0];
                bf0n[j][1] = *(const short8*)&Bs[X1 + brow + j * 1024 + xk1];
            }
        }
        __builtin_amdgcn_s_barrier();
        __builtin_amdgcn_s_setprio(1);
        #pragma unroll
        for (int i = 0; i < 4; ++i)
            #pragma unroll
            for (int j = 0; j < 2; ++j) {
                acc[1][0][i][j] = MFMA(af1[i][0], bf0[j][0], acc[1][0][i][j]);
                acc[1][0][i][j] = MFMA(af1[i][1], bf0[j][1], acc[1][0][i][j]);
            }
        __builtin_amdgcn_s_setprio(0);
        __builtin_amdgcn_s_barrier();
        if (g + 1 < NT) {
            #pragma unroll
            for (int j = 0; j < 2; ++j) {
                bf0[j][0] = bf0n[j][0];
                bf0[j][1] = bf0n[j][1];
            }
        }
    }
#undef STAGE
    #pragma unroll
    for (int mh = 0; mh < 2; ++mh)
        #pragma unroll
        for (int nh = 0; nh < 2; ++nh)
            #pragma unroll
            for (int i = 0; i < 4; ++i)
                #pragma unroll
                for (int j = 0; j < 2; ++j)
                    #pragma unroll
                    for (int r = 0; r < 4; ++r) {
                        int row = A_B0 + mh * 128 + wm * 64 + i * 16 + q * 4 + r;
                        int col = Bw_B0 + nh * 128 + wn * 32 + j * 16 + c;
                        Out[(size_t)row * OC + col] = f2bf(acc[mh][nh][i][j][r]);
                    }
}

// ---------------- 128x128 m97-style GEMM (kept for OC=1024, fp32 out) ----------------
template <int OC, bool OUT_FP32>
__global__ __launch_bounds__(256) void k_gemm(const short* __restrict__ A, const short* __restrict__ Bw,
                                              void* __restrict__ Out) {
    __shared__ short As[128 * 64];
    __shared__ short Bs[128 * 64];
    constexpr int NBX = OC / 128;
    int id = blockIdx.x + blockIdx.y * NBX;
    int fl = (id & 7) * (NBX * 64 / 8) + (id >> 3);
    int bm = fl / NBX, bn = fl % NBX;
    int t = threadIdx.x;
    int wave = t >> 6, lane = t & 63;
    int q = lane >> 4, c = lane & 15;
    int wy = wave >> 1, wx = wave & 1;
    f32x4 acc[4][4] = {};
    int xsw = (c & 7);
    for (int k0 = 0; k0 < C_; k0 += 64) {
        __syncthreads();
        #pragma unroll
        for (int e = 0; e < 4; ++e) {
            int row = (e * 256 + t) >> 3;
            int ks = ((t & 7) ^ (row & 7)) * 8;
            __builtin_amdgcn_global_load_lds(
                (const __attribute__((address_space(1))) void*)&A[(size_t)(bm * 128 + row) * C_ + k0 + ks],
                (__attribute__((address_space(3))) void*)&As[e * 2048 + wave * 512], 16, 0, 0);
            __builtin_amdgcn_global_load_lds(
                (const __attribute__((address_space(1))) void*)&Bw[(size_t)(bn * 128 + row) * C_ + k0 + ks],
                (__attribute__((address_space(3))) void*)&Bs[e * 2048 + wave * 512], 16, 0, 0);
        }
        __syncthreads();
        #pragma unroll
        for (int kk = 0; kk < 64; kk += 32) {
            int o = kk >> 3;
            int xo = ((o + q) ^ xsw) * 8;
            short8 af[4], bfr[4];
            #pragma unroll
            for (int i = 0; i < 4; ++i)
                af[i] = *(const short8*)&As[(wy * 64 + i * 16 + c) * 64 + xo];
            #pragma unroll
            for (int j = 0; j < 4; ++j)
                bfr[j] = *(const short8*)&Bs[(wx * 64 + j * 16 + c) * 64 + xo];
            #pragma unroll
            for (int i = 0; i < 4; ++i)
                #pragma unroll
                for (int j = 0; j < 4; ++j)
                    acc[i][j] = MFMA(af[i], bfr[j], acc[i][j]);
        }
    }
    #pragma unroll
    for (int i = 0; i < 4; ++i)
        #pragma unroll
        for (int j = 0; j < 4; ++j)
            #pragma unroll
            for (int r = 0; r < 4; ++r) {
                int row = bm * 128 + wy * 64 + i * 16 + q * 4 + r;
                int col = bn * 128 + wx * 64 + j * 16 + c;
                if (OUT_FP32) ((float*)Out)[(size_t)row * OC + col] = acc[i][j][r];
                else ((short*)Out)[(size_t)row * OC + col] = f2bf(acc[i][j][r]);
            }
}

// ---------------- k_outer: O_cc = P_cc^T @ P_cc per (b,n,cc), bf16 hi/lo into C slots ----------------
__global__ __launch_bounds__(256) void k_outer(const short* __restrict__ pjqm,
                                               short* __restrict__ Chi, short* __restrict__ Clo) {
    int cc = blockIdx.x, n = blockIdx.y, b = blockIdx.z;   // cc in [0,31)
    int bn = b * NH + n;
    int t = threadIdx.x, wave = t >> 6, lane = t & 63;
    int q = lane >> 4, c = lane & 15;
    __shared__ short Pt_s[64 * 72];   // P_cc^T  [k][v]
    #pragma unroll
    for (int e = 0; e < 2; ++e) {
        int chv = e * 256 + t, row = chv >> 3, sub = chv & 7;
        short8 p8 = *(const short8*)&pjqm[(size_t)(b * W_ + cc * 64 + row) * 2048 + n * KH + sub * 8];
        #pragma unroll
        for (int j = 0; j < 8; ++j) Pt_s[(sub * 8 + j) * 72 + row] = p8[j];
    }
    __syncthreads();
    short8 a0 = *(const short8*)&Pt_s[(wave * 16 + c) * 72 + q * 8];
    short8 a1 = *(const short8*)&Pt_s[(wave * 16 + c) * 72 + 32 + q * 8];
    size_t cbase = ((size_t)bn * 32 + cc) * 4096;
    #pragma unroll
    for (int tj = 0; tj < 4; ++tj) {
        short8 b0 = *(const short8*)&Pt_s[(tj * 16 + c) * 72 + q * 8];
        short8 b1 = *(const short8*)&Pt_s[(tj * 16 + c) * 72 + 32 + q * 8];
        f32x4 acc = {};
        acc = MFMA(a0, b0, acc);
        acc = MFMA(a1, b1, acc);
        s16x4 hi, lo;
        #pragma unroll
        for (int r = 0; r < 4; ++r) {
            float a = acc[r];
            short h = f2bf(a);
            hi[r] = h;
            lo[r] = f2bf(a - bf2f(h));
        }
        size_t off = cbase + (size_t)(tj * 16 + c) * 64 + wave * 16 + q * 4;
        *(s16x4*)&Chi[off] = hi;
        *(s16x4*)&Clo[off] = lo;
    }
}

// ---------------- k_scan: in-place exclusive prefix over the 32 chunk slots ----------------
__global__ __launch_bounds__(256) void k_scan(short* __restrict__ Chi, short* __restrict__ Clo) {
    int bn = blockIdx.y;
    int el = blockIdx.x * 1024 + threadIdx.x * 4;
    size_t off = (size_t)bn * 32 * 4096 + el;
    float run[4] = {0.f, 0.f, 0.f, 0.f};
    s16x4 h = *(const s16x4*)&Chi[off];
    s16x4 l = *(const s16x4*)&Clo[off];
    for (int cc = 0; cc < 31; ++cc) {
        s16x4 nh, nl;
        if (cc < 30) {
            nh = *(const s16x4*)&Chi[off + 4096];
            nl = *(const s16x4*)&Clo[off + 4096];
        }
        s16x4 oh, ol;
        #pragma unroll
        for (int r = 0; r < 4; ++r) {
            float o = bf2f(h[r]) + bf2f(l[r]);
            float cv = run[r];
            short hh = f2bf(cv);
            oh[r] = hh;
            ol[r] = f2bf(cv - bf2f(hh));
            run[r] = cv + o;
        }
        *(s16x4*)&Chi[off] = oh;
        *(s16x4*)&Clo[off] = ol;
        h = nh; l = nl;
        off += 4096;
    }
    s16x4 oh, ol;
    #pragma unroll
    for (int r = 0; r < 4; ++r) {
        short hh = f2bf(run[r]);
        oh[r] = hh;
        ol[r] = f2bf(run[r] - bf2f(hh));
    }
    *(s16x4*)&Chi[off] = oh;
    *(s16x4*)&Clo[off] = ol;
}

// ---------------- k_chunk: nudged_c = causal_intra(QM_c,P_c) + QM_c @ (Chi+Clo) ----------------
__global__ __launch_bounds__(256) void k_chunk(const short* __restrict__ pjqm,
                                               const short* __restrict__ Chi, const short* __restrict__ Clo,
                                               short* __restrict__ Nd) {
    int cc = blockIdx.x, n = blockIdx.y, b = blockIdx.z;
    int t = threadIdx.x, wave = t >> 6, lane = t & 63;
    int q = lane >> 4, c = lane & 15;
    __shared__ short Ps[64 * 72];     // P_c   [v][k]
    __shared__ short Pt_s[64 * 72];   // P_c^T [k][v]
    __shared__ short Ch[64 * 72];     // C_hi  [j][k]
    __shared__ short Cl[64 * 72];     // C_lo  [j][k]
    __shared__ short St[4][16 * 72];  // per-wave S strip [w][v]
    int w0g = b * W_ + cc * 64;

    const short* qmrow = &pjqm[(size_t)(w0g + wave * 16 + c) * 2048 + 1024 + n * KH];
    short8 bq0 = *(const short8*)(qmrow + q * 8);
    short8 bq1 = *(const short8*)(qmrow + 32 + q * 8);

    #pragma unroll
    for (int e = 0; e < 2; ++e) {
        int chv = e * 256 + t, row = chv >> 3, sub = chv & 7;
        short8 p8 = *(const short8*)&pjqm[(size_t)(w0g + row) * 2048 + n * KH + sub * 8];
        *(short8*)&Ps[row * 72 + sub * 8] = p8;
        #pragma unroll
        for (int j = 0; j < 8; ++j) Pt_s[(sub * 8 + j) * 72 + row] = p8[j];
        size_t cbase = ((size_t)((b * NH + n) * 32 + cc)) * 4096;
        *(short8*)&Ch[row * 72 + sub * 8] = *(const short8*)&Chi[cbase + row * 64 + sub * 8];
        *(short8*)&Cl[row * 72 + sub * 8] = *(const short8*)&Clo[cbase + row * 64 + sub * 8];
    }
    __syncthreads();
    #pragma unroll
    for (int ct = 0; ct < 4; ++ct) {
        short8 a0 = *(const short8*)&Ps[(ct * 16 + c) * 72 + q * 8];
        short8 a1 = *(const short8*)&Ps[(ct * 16 + c) * 72 + 32 + q * 8];
        f32x4 s = {};
        s = MFMA(a0, bq0, s);
        s = MFMA(a1, bq1, s);
        int vb = ct * 16 + q * 4, wl = wave * 16 + c;
        s16x4 pk;
        #pragma unroll
        for (int r = 0; r < 4; ++r) {
            float v = s[r];
            if (vb + r > wl) v = 0.f;
            pk[r] = f2bf(v);
        }
        *(s16x4*)&St[wave][c * 72 + ct * 16 + q * 4] = pk;
    }
    __syncthreads();
    f32x4 oc[4] = {};
    short8 as0 = *(const short8*)&St[wave][c * 72 + q * 8];
    short8 as1 = *(const short8*)&St[wave][c * 72 + 32 + q * 8];
    #pragma unroll
    for (int tj = 0; tj < 4; ++tj) {
        short8 bp0 = *(const short8*)&Pt_s[(tj * 16 + c) * 72 + q * 8];
        short8 bp1 = *(const short8*)&Pt_s[(tj * 16 + c) * 72 + 32 + q * 8];
        oc[tj] = MFMA(as0, bp0, oc[tj]);
        oc[tj] = MFMA(as1, bp1, oc[tj]);
        short8 bh0 = *(const short8*)&Ch[(tj * 16 + c) * 72 + q * 8];
        short8 bh1 = *(const short8*)&Ch[(tj * 16 + c) * 72 + 32 + q * 8];
        oc[tj] = MFMA(bq0, bh0, oc[tj]);
        oc[tj] = MFMA(bq1, bh1, oc[tj]);
        short8 bl0 = *(const short8*)&Cl[(tj * 16 + c) * 72 + q * 8];
        short8 bl1 = *(const short8*)&Cl[(tj * 16 + c) * 72 + 32 + q * 8];
        oc[tj] = MFMA(bq0, bl0, oc[tj]);
        oc[tj] = MFMA(bq1, bl1, oc[tj]);
    }
    #pragma unroll
    for (int tj = 0; tj < 4; ++tj)
        #pragma unroll
        for (int r = 0; r < 4; ++r)
            Nd[(size_t)(w0g + wave * 16 + q * 4 + r) * C_ + n * KH + tj * 16 + c] = f2bf(oc[tj][r]);
}

extern "C" void kernel_launch(void* const* d_in, const int* in_sizes, int n_in,
                              void* d_out, int out_size, void* d_ws, size_t ws_size,
                              hipStream_t stream) {
    const float* x  = (const float*)d_in[0];
    const float* Wp = (const float*)d_in[1];
    const float* Pm = (const float*)d_in[2];
    const float* Tr = (const float*)d_in[3];
    const float* Wm = (const float*)d_in[4];
    float* out = (float*)d_out;
    char* ws = (char*)d_ws;

    const size_t MB = 1024 * 1024;
    float* metric = (float*)ws;                        // 256 KB
    short* wcat  = (short*)(ws + 256 * 1024);          // 4 MB: [Wp(1024) ; Wq(1024)] x 1024
    short* wp16  = wcat;
    short* wq16  = wcat + C_ * C_;
    short* wf16  = (short*)(ws + 256 * 1024 + 4 * MB); // 2 MB
    short* x16   = (short*)(ws + 256 * 1024 + 6 * MB); // 16 MB (aliased by nd16 later)
    short* pjqm  = (short*)(ws + 256 * 1024 + 22 * MB);// 32 MB: [8192][2048] = [proj | qm]
    short* nd16  = x16;                                // x16 dead after concat GEMM
    short* Chi   = (short*)d_out;                      // d_out as scratch: 16.75 MB
    short* Clo   = Chi + 8 * MB;                       // 16.75 MB (exactly fills d_out)

    k_metric<<<dim3(NH), dim3(256), 0, stream>>>(Pm, metric);
    k_wq<<<dim3(16, NH), dim3(256), 0, stream>>>(metric, Wp, wq16);
    k_wf<<<dim3(16, NH), dim3(256), 0, stream>>>(Tr, Wm, wf16);
    k_cvt<<<dim3(8192), dim3(256), 0, stream>>>(x, x16, (B_ * W_ * C_) / 4);
    k_cvt<<<dim3(1024), dim3(256), 0, stream>>>(Wp, wp16, (C_ * C_) / 4);

    k_gemm256<2048><<<dim3(8, 32), dim3(512), 0, stream>>>(x16, wcat, pjqm);
    k_outer<<<dim3(31, NH, B_), dim3(256), 0, stream>>>(pjqm, Chi, Clo);
    k_scan<<<dim3(4, 64), dim3(256), 0, stream>>>(Chi, Clo);
    k_chunk<<<dim3(32, NH, B_), dim3(256), 0, stream>>>(pjqm, Chi, Clo, nd16);
    k_gemm<1024, true><<<dim3(8, 64), dim3(256), 0, stream>>>(nd16, wf16, (void*)out);
}

// Round 6
// 217.720 us; speedup vs baseline: 1.1360x; 1.1360x over previous
//
#include <hip/hip_runtime.h>

#define B_ 4
#define W_ 2048
#define C_ 1024
#define NH 16
#define KH 64

typedef __attribute__((ext_vector_type(8))) short short8;
typedef __attribute__((ext_vector_type(4))) short s16x4;
typedef __attribute__((ext_vector_type(4))) float f32x4;

__device__ __forceinline__ short f2bf(float f) {
    unsigned u = __builtin_bit_cast(unsigned, f);
    u = (u + 0x7FFFu + ((u >> 16) & 1u)) >> 16;
    return (short)u;
}
__device__ __forceinline__ float bf2f(short h) {
    return __builtin_bit_cast(float, ((unsigned)(unsigned short)h) << 16);
}

#define MFMA(a, b, cc) __builtin_amdgcn_mfma_f32_16x16x32_bf16(a, b, cc, 0, 0, 0)

// ---------------- metric[n] = P[n] @ P[n]^T ----------------
__global__ __launch_bounds__(256) void k_metric(const float* __restrict__ P, float* __restrict__ M) {
    int n = blockIdx.x;
    __shared__ float sP[KH * KH];
    __shared__ float sPt[KH * 65];
    const float* Pn = P + n * KH * KH;
    for (int i = threadIdx.x; i < KH * KH; i += 256) {
        float v = Pn[i];
        sP[i] = v;
        sPt[(i & 63) * 65 + (i >> 6)] = v;
    }
    __syncthreads();
    float* Mn = M + n * KH * KH;
    for (int e = threadIdx.x; e < KH * KH; e += 256) {
        int i = e >> 6, k = e & 63;
        float s = 0.f;
        #pragma unroll 8
        for (int j = 0; j < KH; ++j) s += sP[i * KH + j] * sPt[j * 65 + k];
        Mn[e] = s;
    }
}

// ---------------- Wf[o][n*64+k] = sum_j T[n][k][j] * Wm[o][n*64+j] ----------------
__global__ __launch_bounds__(256) void k_wf(const float* __restrict__ T, const float* __restrict__ Wm,
                                            short* __restrict__ Wf) {
    int n = blockIdx.y, oseg = blockIdx.x;
    __shared__ float sTt[KH * 65];
    __shared__ float sW[KH * KH];
    for (int i = threadIdx.x; i < KH * KH; i += 256) {
        sTt[(i & 63) * 65 + (i >> 6)] = T[n * KH * KH + i];
        int r = i >> 6, c = i & 63;
        sW[i] = Wm[(oseg * KH + r) * C_ + n * KH + c];
    }
    __syncthreads();
    for (int e = threadIdx.x; e < KH * KH; e += 256) {
        int r = e >> 6, k = e & 63;
        float s = 0.f;
        #pragma unroll 8
        for (int j = 0; j < KH; ++j) s += sTt[j * 65 + k] * sW[r * KH + j];
        Wf[(oseg * KH + r) * C_ + n * KH + k] = f2bf(s);
    }
}

// ---------------- fp32 -> bf16 convert ----------------
__global__ __launch_bounds__(256) void k_cvt(const float* __restrict__ src, short* __restrict__ dst, int n4) {
    int i = blockIdx.x * 256 + threadIdx.x;
    if (i < n4) {
        float4 v = ((const float4*)src)[i];
        short4 o;
        o.x = f2bf(v.x); o.y = f2bf(v.y); o.z = f2bf(v.z); o.w = f2bf(v.w);
        ((short4*)dst)[i] = o;
    }
}

// ---------------- 128x128 m97-style GEMM: Out[M][col] = A[M][1024] @ Bw[col][1024]^T --------
// STRIDE = row stride of Out (lets proj land in pjqm's left half).
template <int OC, int STRIDE, bool OUT_FP32>
__global__ __launch_bounds__(256) void k_gemm(const short* __restrict__ A, const short* __restrict__ Bw,
                                              void* __restrict__ Out) {
    __shared__ short As[128 * 64];
    __shared__ short Bs[128 * 64];
    // T1: bijective XCD swizzle (grid = (OC/128) * 64 blocks, %8 == 0)
    constexpr int NBX = OC / 128;
    int id = blockIdx.x + blockIdx.y * NBX;
    int fl = (id & 7) * (NBX * 64 / 8) + (id >> 3);
    int bm = fl / NBX, bn = fl % NBX;
    int t = threadIdx.x;
    int wave = t >> 6, lane = t & 63;
    int q = lane >> 4, c = lane & 15;
    int wy = wave >> 1, wx = wave & 1;
    f32x4 acc[4][4] = {};
    int xsw = (c & 7);                       // reader-side swizzle
    for (int k0 = 0; k0 < C_; k0 += 64) {
        __syncthreads();
        #pragma unroll
        for (int e = 0; e < 4; ++e) {
            int row = (e * 256 + t) >> 3;
            int ks = ((t & 7) ^ (row & 7)) * 8;          // swizzled k-chunk (global side)
            __builtin_amdgcn_global_load_lds(
                (const __attribute__((address_space(1))) void*)&A[(size_t)(bm * 128 + row) * C_ + k0 + ks],
                (__attribute__((address_space(3))) void*)&As[e * 2048 + wave * 512], 16, 0, 0);
            __builtin_amdgcn_global_load_lds(
                (const __attribute__((address_space(1))) void*)&Bw[(size_t)(bn * 128 + row) * C_ + k0 + ks],
                (__attribute__((address_space(3))) void*)&Bs[e * 2048 + wave * 512], 16, 0, 0);
        }
        __syncthreads();
        #pragma unroll
        for (int kk = 0; kk < 64; kk += 32) {
            int o = kk >> 3;                             // 0 or 4
            int xo = ((o + q) ^ xsw) * 8;
            short8 af[4], bfr[4];
            #pragma unroll
            for (int i = 0; i < 4; ++i)
                af[i] = *(const short8*)&As[(wy * 64 + i * 16 + c) * 64 + xo];
            #pragma unroll
            for (int j = 0; j < 4; ++j)
                bfr[j] = *(const short8*)&Bs[(wx * 64 + j * 16 + c) * 64 + xo];
            #pragma unroll
            for (int i = 0; i < 4; ++i)
                #pragma unroll
                for (int j = 0; j < 4; ++j)
                    acc[i][j] = MFMA(af[i], bfr[j], acc[i][j]);
        }
    }
    #pragma unroll
    for (int i = 0; i < 4; ++i)
        #pragma unroll
        for (int j = 0; j < 4; ++j)
            #pragma unroll
            for (int r = 0; r < 4; ++r) {
                int row = bm * 128 + wy * 64 + i * 16 + q * 4 + r;
                int col = bn * 128 + wx * 64 + j * 16 + c;
                if (OUT_FP32) ((float*)Out)[(size_t)row * STRIDE + col] = acc[i][j][r];
                else ((short*)Out)[(size_t)row * STRIDE + col] = f2bf(acc[i][j][r]);
            }
}

// ---------------- k_qm: qm[w][n*64+j] = sum_k proj[w][n*64+k] * (0.125*M_n)[j][k] ----------------
// Replaces the qm half of the old OC=2048 GEMM (K=64 instead of K=1024: 16x fewer FLOPs).
// grid (32 row-chunks, 16 heads) x 256 thr (4 waves x 64 rows). M symmetric -> [j][k] = metric rows.
__global__ __launch_bounds__(256) void k_qm(const short* __restrict__ pjqm_in,
                                            const float* __restrict__ metric,
                                            short* __restrict__ pjqm_out) {
    int bm = blockIdx.x, n = blockIdx.y;
    int t = threadIdx.x, wave = t >> 6, lane = t & 63;
    int q = lane >> 4, c = lane & 15;
    __shared__ short Mb[64 * 72];     // 0.125 * M_n, [j][k]
    const float* Mn = metric + n * 4096;
    #pragma unroll
    for (int e = 0; e < 4; ++e) {
        int i4 = e * 256 + t;                          // float4 index, 1024 total
        float4 v = ((const float4*)Mn)[i4];
        s16x4 o;
        o[0] = f2bf(v.x * 0.125f); o[1] = f2bf(v.y * 0.125f);
        o[2] = f2bf(v.z * 0.125f); o[3] = f2bf(v.w * 0.125f);
        int row = i4 >> 4, col = (i4 & 15) * 4;
        *(s16x4*)&Mb[row * 72 + col] = o;
    }
    __syncthreads();
    short8 b0[4], b1[4];
    #pragma unroll
    for (int ct = 0; ct < 4; ++ct) {
        b0[ct] = *(const short8*)&Mb[(ct * 16 + c) * 72 + q * 8];
        b1[ct] = *(const short8*)&Mb[(ct * 16 + c) * 72 + 32 + q * 8];
    }
    int rbase = bm * 256 + wave * 64;
    #pragma unroll
    for (int rt = 0; rt < 4; ++rt) {
        const short* arow = &pjqm_in[(size_t)(rbase + rt * 16 + c) * 2048 + n * KH];
        short8 a0 = *(const short8*)(arow + q * 8);
        short8 a1 = *(const short8*)(arow + 32 + q * 8);
        #pragma unroll
        for (int ct = 0; ct < 4; ++ct) {
            f32x4 acc = {};
            acc = MFMA(a0, b0[ct], acc);
            acc = MFMA(a1, b1[ct], acc);
            #pragma unroll
            for (int r = 0; r < 4; ++r)
                pjqm_out[(size_t)(rbase + rt * 16 + q * 4 + r) * 2048 + 1024 + n * KH + ct * 16 + c] =
                    f2bf(acc[r]);
        }
    }
}

// ---------------- k_outer: O_cc = P_cc^T @ P_cc per (b,n,cc), bf16 hi/lo into C slots ----------------
__global__ __launch_bounds__(256) void k_outer(const short* __restrict__ pjqm,
                                               short* __restrict__ Chi, short* __restrict__ Clo) {
    int cc = blockIdx.x, n = blockIdx.y, b = blockIdx.z;   // cc in [0,31)
    int bn = b * NH + n;
    int t = threadIdx.x, wave = t >> 6, lane = t & 63;
    int q = lane >> 4, c = lane & 15;
    __shared__ short Pt_s[64 * 72];   // P_cc^T  [k][v]
    #pragma unroll
    for (int e = 0; e < 2; ++e) {
        int chv = e * 256 + t, row = chv >> 3, sub = chv & 7;
        short8 p8 = *(const short8*)&pjqm[(size_t)(b * W_ + cc * 64 + row) * 2048 + n * KH + sub * 8];
        #pragma unroll
        for (int j = 0; j < 8; ++j) Pt_s[(sub * 8 + j) * 72 + row] = p8[j];
    }
    __syncthreads();
    short8 a0 = *(const short8*)&Pt_s[(wave * 16 + c) * 72 + q * 8];
    short8 a1 = *(const short8*)&Pt_s[(wave * 16 + c) * 72 + 32 + q * 8];
    size_t cbase = ((size_t)bn * 32 + cc) * 4096;
    #pragma unroll
    for (int tj = 0; tj < 4; ++tj) {
        short8 b0 = *(const short8*)&Pt_s[(tj * 16 + c) * 72 + q * 8];
        short8 b1 = *(const short8*)&Pt_s[(tj * 16 + c) * 72 + 32 + q * 8];
        f32x4 acc = {};
        acc = MFMA(a0, b0, acc);
        acc = MFMA(a1, b1, acc);
        s16x4 hi, lo;
        #pragma unroll
        for (int r = 0; r < 4; ++r) {
            float a = acc[r];
            short h = f2bf(a);
            hi[r] = h;
            lo[r] = f2bf(a - bf2f(h));
        }
        size_t off = cbase + (size_t)(tj * 16 + c) * 64 + wave * 16 + q * 4;
        *(s16x4*)&Chi[off] = hi;
        *(s16x4*)&Clo[off] = lo;
    }
}

// ---------------- k_scan: in-place exclusive prefix over the 32 chunk slots ----------------
__global__ __launch_bounds__(256) void k_scan(short* __restrict__ Chi, short* __restrict__ Clo) {
    int bn = blockIdx.y;
    int el = blockIdx.x * 1024 + threadIdx.x * 4;
    size_t off = (size_t)bn * 32 * 4096 + el;
    float run[4] = {0.f, 0.f, 0.f, 0.f};
    s16x4 h = *(const s16x4*)&Chi[off];
    s16x4 l = *(const s16x4*)&Clo[off];
    for (int cc = 0; cc < 31; ++cc) {
        s16x4 nh, nl;
        if (cc < 30) {
            nh = *(const s16x4*)&Chi[off + 4096];
            nl = *(const s16x4*)&Clo[off + 4096];
        }
        s16x4 oh, ol;
        #pragma unroll
        for (int r = 0; r < 4; ++r) {
            float o = bf2f(h[r]) + bf2f(l[r]);
            float cv = run[r];
            short hh = f2bf(cv);
            oh[r] = hh;
            ol[r] = f2bf(cv - bf2f(hh));
            run[r] = cv + o;
        }
        *(s16x4*)&Chi[off] = oh;
        *(s16x4*)&Clo[off] = ol;
        h = nh; l = nl;
        off += 4096;
    }
    s16x4 oh, ol;
    #pragma unroll
    for (int r = 0; r < 4; ++r) {
        short hh = f2bf(run[r]);
        oh[r] = hh;
        ol[r] = f2bf(run[r] - bf2f(hh));
    }
    *(s16x4*)&Chi[off] = oh;
    *(s16x4*)&Clo[off] = ol;
}

// ---------------- k_chunk: nudged_c = causal_intra(QM_c,P_c) + QM_c @ (Chi+Clo) ----------------
__global__ __launch_bounds__(256) void k_chunk(const short* __restrict__ pjqm,
                                               const short* __restrict__ Chi, const short* __restrict__ Clo,
                                               short* __restrict__ Nd) {
    int cc = blockIdx.x, n = blockIdx.y, b = blockIdx.z;
    int t = threadIdx.x, wave = t >> 6, lane = t & 63;
    int q = lane >> 4, c = lane & 15;
    __shared__ short Ps[64 * 72];     // P_c   [v][k]
    __shared__ short Pt_s[64 * 72];   // P_c^T [k][v]
    __shared__ short Ch[64 * 72];     // C_hi  [j][k]
    __shared__ short Cl[64 * 72];     // C_lo  [j][k]
    __shared__ short St[4][16 * 72];  // per-wave S strip [w][v]
    int w0g = b * W_ + cc * 64;

    const short* qmrow = &pjqm[(size_t)(w0g + wave * 16 + c) * 2048 + 1024 + n * KH];
    short8 bq0 = *(const short8*)(qmrow + q * 8);
    short8 bq1 = *(const short8*)(qmrow + 32 + q * 8);

    #pragma unroll
    for (int e = 0; e < 2; ++e) {
        int chv = e * 256 + t, row = chv >> 3, sub = chv & 7;
        short8 p8 = *(const short8*)&pjqm[(size_t)(w0g + row) * 2048 + n * KH + sub * 8];
        *(short8*)&Ps[row * 72 + sub * 8] = p8;
        #pragma unroll
        for (int j = 0; j < 8; ++j) Pt_s[(sub * 8 + j) * 72 + row] = p8[j];
        size_t cbase = ((size_t)((b * NH + n) * 32 + cc)) * 4096;
        *(short8*)&Ch[row * 72 + sub * 8] = *(const short8*)&Chi[cbase + row * 64 + sub * 8];
        *(short8*)&Cl[row * 72 + sub * 8] = *(const short8*)&Clo[cbase + row * 64 + sub * 8];
    }
    __syncthreads();
    #pragma unroll
    for (int ct = 0; ct < 4; ++ct) {
        short8 a0 = *(const short8*)&Ps[(ct * 16 + c) * 72 + q * 8];
        short8 a1 = *(const short8*)&Ps[(ct * 16 + c) * 72 + 32 + q * 8];
        f32x4 s = {};
        s = MFMA(a0, bq0, s);
        s = MFMA(a1, bq1, s);
        int vb = ct * 16 + q * 4, wl = wave * 16 + c;
        s16x4 pk;
        #pragma unroll
        for (int r = 0; r < 4; ++r) {
            float v = s[r];
            if (vb + r > wl) v = 0.f;
            pk[r] = f2bf(v);
        }
        *(s16x4*)&St[wave][c * 72 + ct * 16 + q * 4] = pk;
    }
    __syncthreads();
    f32x4 oc[4] = {};
    short8 as0 = *(const short8*)&St[wave][c * 72 + q * 8];
    short8 as1 = *(const short8*)&St[wave][c * 72 + 32 + q * 8];
    #pragma unroll
    for (int tj = 0; tj < 4; ++tj) {
        short8 bp0 = *(const short8*)&Pt_s[(tj * 16 + c) * 72 + q * 8];
        short8 bp1 = *(const short8*)&Pt_s[(tj * 16 + c) * 72 + 32 + q * 8];
        oc[tj] = MFMA(as0, bp0, oc[tj]);
        oc[tj] = MFMA(as1, bp1, oc[tj]);
        short8 bh0 = *(const short8*)&Ch[(tj * 16 + c) * 72 + q * 8];
        short8 bh1 = *(const short8*)&Ch[(tj * 16 + c) * 72 + 32 + q * 8];
        oc[tj] = MFMA(bq0, bh0, oc[tj]);
        oc[tj] = MFMA(bq1, bh1, oc[tj]);
        short8 bl0 = *(const short8*)&Cl[(tj * 16 + c) * 72 + q * 8];
        short8 bl1 = *(const short8*)&Cl[(tj * 16 + c) * 72 + 32 + q * 8];
        oc[tj] = MFMA(bq0, bl0, oc[tj]);
        oc[tj] = MFMA(bq1, bl1, oc[tj]);
    }
    #pragma unroll
    for (int tj = 0; tj < 4; ++tj)
        #pragma unroll
        for (int r = 0; r < 4; ++r)
            Nd[(size_t)(w0g + wave * 16 + q * 4 + r) * C_ + n * KH + tj * 16 + c] = f2bf(oc[tj][r]);
}

extern "C" void kernel_launch(void* const* d_in, const int* in_sizes, int n_in,
                              void* d_out, int out_size, void* d_ws, size_t ws_size,
                              hipStream_t stream) {
    const float* x  = (const float*)d_in[0];
    const float* Wp = (const float*)d_in[1];
    const float* Pm = (const float*)d_in[2];
    const float* Tr = (const float*)d_in[3];
    const float* Wm = (const float*)d_in[4];
    float* out = (float*)d_out;
    char* ws = (char*)d_ws;

    const size_t MB = 1024 * 1024;
    float* metric = (float*)ws;                        // 256 KB (fp32, consumed by k_qm)
    short* wp16  = (short*)(ws + 256 * 1024);          // 2 MB
    short* wf16  = (short*)(ws + 256 * 1024 + 4 * MB); // 2 MB
    short* x16   = (short*)(ws + 256 * 1024 + 6 * MB); // 16 MB (aliased by nd16 later)
    short* pjqm  = (short*)(ws + 256 * 1024 + 22 * MB);// 32 MB: [8192][2048] = [proj | qm]
    short* nd16  = x16;                                // x16 dead after GEMM1
    short* Chi   = (short*)d_out;                      // d_out as scratch: 16.75 MB
    short* Clo   = Chi + 8 * MB;                       // 16.75 MB (exactly fills d_out)

    k_metric<<<dim3(NH), dim3(256), 0, stream>>>(Pm, metric);
    k_wf<<<dim3(16, NH), dim3(256), 0, stream>>>(Tr, Wm, wf16);
    k_cvt<<<dim3(8192), dim3(256), 0, stream>>>(x, x16, (B_ * W_ * C_) / 4);
    k_cvt<<<dim3(1024), dim3(256), 0, stream>>>(Wp, wp16, (C_ * C_) / 4);

    // proj into pjqm left half (OC=1024, row stride 2048)
    k_gemm<1024, 2048, false><<<dim3(8, 64), dim3(256), 0, stream>>>(x16, wp16, (void*)pjqm);
    // qm = proj @ (M/8) per head into pjqm right half (K=64)
    k_qm<<<dim3(32, NH), dim3(256), 0, stream>>>(pjqm, metric, pjqm);
    k_outer<<<dim3(31, NH, B_), dim3(256), 0, stream>>>(pjqm, Chi, Clo);
    k_scan<<<dim3(4, 64), dim3(256), 0, stream>>>(Chi, Clo);
    k_chunk<<<dim3(32, NH, B_), dim3(256), 0, stream>>>(pjqm, Chi, Clo, nd16);
    k_gemm<1024, 1024, true><<<dim3(8, 64), dim3(256), 0, stream>>>(nd16, wf16, (void*)out);
}

// Round 7
// 210.288 us; speedup vs baseline: 1.1761x; 1.0353x over previous
//
#include <hip/hip_runtime.h>

#define B_ 4
#define W_ 2048
#define C_ 1024
#define NH 16
#define KH 64

typedef __attribute__((ext_vector_type(8))) short short8;
typedef __attribute__((ext_vector_type(4))) short s16x4;
typedef __attribute__((ext_vector_type(4))) float f32x4;

__device__ __forceinline__ short f2bf(float f) {
    unsigned u = __builtin_bit_cast(unsigned, f);
    u = (u + 0x7FFFu + ((u >> 16) & 1u)) >> 16;
    return (short)u;
}
__device__ __forceinline__ float bf2f(short h) {
    return __builtin_bit_cast(float, ((unsigned)(unsigned short)h) << 16);
}

#define MFMA(a, b, cc) __builtin_amdgcn_mfma_f32_16x16x32_bf16(a, b, cc, 0, 0, 0)

// ---------------- k_prep: fused {cvt x, cvt Wp, Wf build, metric} (independent prep work) ------
// bid <  8192        : x fp32 -> bf16                      (x16)
// bid <  9216        : Wp fp32 -> bf16                     (wp16)
// bid <  9472 (256)  : Wf[o][n*64+k] = sum_j T[n][k][j] * Wm[o][n*64+j]
// bid <  9488 (16)   : metric[n] = P[n] @ P[n]^T           (fp32, consumed by k_outer)
__global__ __launch_bounds__(256) void k_prep(const float* __restrict__ x, const float* __restrict__ Wp,
                                              const float* __restrict__ Pm, const float* __restrict__ Tr,
                                              const float* __restrict__ Wm,
                                              short* __restrict__ x16, short* __restrict__ wp16,
                                              short* __restrict__ wf16, float* __restrict__ metric) {
    int bid = blockIdx.x, t = threadIdx.x;
    __shared__ float sA[KH * 65];
    __shared__ float sB[KH * KH];
    if (bid < 8192) {
        int i = bid * 256 + t;
        float4 v = ((const float4*)x)[i];
        short4 o;
        o.x = f2bf(v.x); o.y = f2bf(v.y); o.z = f2bf(v.z); o.w = f2bf(v.w);
        ((short4*)x16)[i] = o;
    } else if (bid < 9216) {
        int i = (bid - 8192) * 256 + t;
        float4 v = ((const float4*)Wp)[i];
        short4 o;
        o.x = f2bf(v.x); o.y = f2bf(v.y); o.z = f2bf(v.z); o.w = f2bf(v.w);
        ((short4*)wp16)[i] = o;
    } else if (bid < 9472) {
        int idx = bid - 9216;
        int oseg = idx & 15, n = idx >> 4;
        for (int i = t; i < KH * KH; i += 256) {
            sA[(i & 63) * 65 + (i >> 6)] = Tr[n * KH * KH + i];   // T^T
            int r = i >> 6, c = i & 63;
            sB[i] = Wm[(oseg * KH + r) * C_ + n * KH + c];
        }
        __syncthreads();
        for (int e = t; e < KH * KH; e += 256) {
            int r = e >> 6, k = e & 63;
            float s = 0.f;
            #pragma unroll 8
            for (int j = 0; j < KH; ++j) s += sA[j * 65 + k] * sB[r * KH + j];
            wf16[(oseg * KH + r) * C_ + n * KH + k] = f2bf(s);
        }
    } else {
        int n = bid - 9472;
        const float* Pn = Pm + n * KH * KH;
        for (int i = t; i < KH * KH; i += 256) {
            float v = Pn[i];
            sB[i] = v;
            sA[(i & 63) * 65 + (i >> 6)] = v;                      // P^T
        }
        __syncthreads();
        float* Mn = metric + n * KH * KH;
        for (int e = t; e < KH * KH; e += 256) {
            int i = e >> 6, k = e & 63;
            float s = 0.f;
            #pragma unroll 8
            for (int j = 0; j < KH; ++j) s += sB[i * KH + j] * sA[j * 65 + k];
            Mn[e] = s;
        }
    }
}

// ---------------- 128x64-tile m97-style GEMM: Out[M][col] = A[M][1024] @ Bw[col][1024]^T --------
// BN=64 -> grid (OC/64, 64) = 1024 blocks = 4 blocks/CU (vs 2 at BN=128): more implicit
// wave-overlap for the latency-bound m97 structure. STRIDE = Out row stride.
template <int OC, int STRIDE, bool OUT_FP32>
__global__ __launch_bounds__(256) void k_gemm(const short* __restrict__ A, const short* __restrict__ Bw,
                                              void* __restrict__ Out) {
    __shared__ short As[128 * 64];
    __shared__ short Bs[64 * 64];
    constexpr int NBX = OC / 64;
    int id = blockIdx.x + blockIdx.y * NBX;
    int fl = (id & 7) * (NBX * 64 / 8) + (id >> 3);   // bijective XCD swizzle (grid %8==0)
    int bm = fl / NBX, bn = fl % NBX;
    int t = threadIdx.x;
    int wave = t >> 6, lane = t & 63;
    int q = lane >> 4, c = lane & 15;
    int wy = wave >> 1, wx = wave & 1;                 // wave tile: 64 rows x 32 cols
    f32x4 acc[4][2] = {};
    int xsw = (c & 7);
    for (int k0 = 0; k0 < C_; k0 += 64) {
        __syncthreads();
        #pragma unroll
        for (int e = 0; e < 4; ++e) {
            int row = (e * 256 + t) >> 3;
            int ks = ((t & 7) ^ (row & 7)) * 8;
            __builtin_amdgcn_global_load_lds(
                (const __attribute__((address_space(1))) void*)&A[(size_t)(bm * 128 + row) * C_ + k0 + ks],
                (__attribute__((address_space(3))) void*)&As[e * 2048 + wave * 512], 16, 0, 0);
        }
        #pragma unroll
        for (int e = 0; e < 2; ++e) {
            int row = (e * 256 + t) >> 3;
            int ks = ((t & 7) ^ (row & 7)) * 8;
            __builtin_amdgcn_global_load_lds(
                (const __attribute__((address_space(1))) void*)&Bw[(size_t)(bn * 64 + row) * C_ + k0 + ks],
                (__attribute__((address_space(3))) void*)&Bs[e * 2048 + wave * 512], 16, 0, 0);
        }
        __syncthreads();
        #pragma unroll
        for (int kk = 0; kk < 64; kk += 32) {
            int o = kk >> 3;
            int xo = ((o + q) ^ xsw) * 8;
            short8 af[4], bfr[2];
            #pragma unroll
            for (int i = 0; i < 4; ++i)
                af[i] = *(const short8*)&As[(wy * 64 + i * 16 + c) * 64 + xo];
            #pragma unroll
            for (int j = 0; j < 2; ++j)
                bfr[j] = *(const short8*)&Bs[(wx * 32 + j * 16 + c) * 64 + xo];
            #pragma unroll
            for (int i = 0; i < 4; ++i)
                #pragma unroll
                for (int j = 0; j < 2; ++j)
                    acc[i][j] = MFMA(af[i], bfr[j], acc[i][j]);
        }
    }
    #pragma unroll
    for (int i = 0; i < 4; ++i)
        #pragma unroll
        for (int j = 0; j < 2; ++j)
            #pragma unroll
            for (int r = 0; r < 4; ++r) {
                int row = bm * 128 + wy * 64 + i * 16 + q * 4 + r;
                int col = bn * 64 + wx * 32 + j * 16 + c;
                if (OUT_FP32) ((float*)Out)[(size_t)row * STRIDE + col] = acc[i][j][r];
                else ((short*)Out)[(size_t)row * STRIDE + col] = f2bf(acc[i][j][r]);
            }
}

// ---------------- k_outer (fused qm): per (b,n,cc 64-row chunk) ----------------
// Always: qm[w][n*64+j] = sum_k proj[w][n*64+k] * (0.125*M_n)[j][k]  (K=64 MFMA, 8/wave)
// cc<31 : O_cc = P_cc^T @ P_cc -> bf16 hi/lo into Chi/Clo slot        (8 MFMA/wave)
__global__ __launch_bounds__(256) void k_outer(short* __restrict__ pjqm,
                                               const float* __restrict__ metric,
                                               short* __restrict__ Chi, short* __restrict__ Clo) {
    int cc = blockIdx.x, n = blockIdx.y, b = blockIdx.z;
    int bn = b * NH + n;
    int t = threadIdx.x, wave = t >> 6, lane = t & 63;
    int q = lane >> 4, c = lane & 15;
    int w0g = b * W_ + cc * 64;
    __shared__ short Pt_s[64 * 72];   // P_cc^T [k][v]
    __shared__ short Mb[64 * 72];     // 0.125 * M_n, [j][k]

    // stage Mb (always)
    const float* Mn = metric + n * 4096;
    #pragma unroll
    for (int e = 0; e < 4; ++e) {
        int i4 = e * 256 + t;
        float4 v = ((const float4*)Mn)[i4];
        s16x4 o;
        o[0] = f2bf(v.x * 0.125f); o[1] = f2bf(v.y * 0.125f);
        o[2] = f2bf(v.z * 0.125f); o[3] = f2bf(v.w * 0.125f);
        int row = i4 >> 4, col = (i4 & 15) * 4;
        *(s16x4*)&Mb[row * 72 + col] = o;
    }
    // stage P^T (only needed for O)
    if (cc < 31) {
        #pragma unroll
        for (int e = 0; e < 2; ++e) {
            int chv = e * 256 + t, row = chv >> 3, sub = chv & 7;
            short8 p8 = *(const short8*)&pjqm[(size_t)(w0g + row) * 2048 + n * KH + sub * 8];
            #pragma unroll
            for (int j = 0; j < 8; ++j) Pt_s[(sub * 8 + j) * 72 + row] = p8[j];
        }
    }
    __syncthreads();

    // qm: each wave handles its 16 rows (A-frags straight from global, L2-hot)
    {
        const short* arow = &pjqm[(size_t)(w0g + wave * 16 + c) * 2048 + n * KH];
        short8 a0 = *(const short8*)(arow + q * 8);
        short8 a1 = *(const short8*)(arow + 32 + q * 8);
        #pragma unroll
        for (int ct = 0; ct < 4; ++ct) {
            short8 b0 = *(const short8*)&Mb[(ct * 16 + c) * 72 + q * 8];
            short8 b1 = *(const short8*)&Mb[(ct * 16 + c) * 72 + 32 + q * 8];
            f32x4 acc = {};
            acc = MFMA(a0, b0, acc);
            acc = MFMA(a1, b1, acc);
            #pragma unroll
            for (int r = 0; r < 4; ++r)
                pjqm[(size_t)(w0g + wave * 16 + q * 4 + r) * 2048 + 1024 + n * KH + ct * 16 + c] =
                    f2bf(acc[r]);
        }
    }

    if (cc < 31) {
        short8 a0 = *(const short8*)&Pt_s[(wave * 16 + c) * 72 + q * 8];
        short8 a1 = *(const short8*)&Pt_s[(wave * 16 + c) * 72 + 32 + q * 8];
        size_t cbase = ((size_t)bn * 32 + cc) * 4096;
        #pragma unroll
        for (int tj = 0; tj < 4; ++tj) {
            short8 b0 = *(const short8*)&Pt_s[(tj * 16 + c) * 72 + q * 8];
            short8 b1 = *(const short8*)&Pt_s[(tj * 16 + c) * 72 + 32 + q * 8];
            f32x4 acc = {};
            acc = MFMA(a0, b0, acc);
            acc = MFMA(a1, b1, acc);
            s16x4 hi, lo;
            #pragma unroll
            for (int r = 0; r < 4; ++r) {
                float a = acc[r];
                short h = f2bf(a);
                hi[r] = h;
                lo[r] = f2bf(a - bf2f(h));
            }
            size_t off = cbase + (size_t)(tj * 16 + c) * 64 + wave * 16 + q * 4;  // [j][k], sym
            *(s16x4*)&Chi[off] = hi;
            *(s16x4*)&Clo[off] = lo;
        }
    }
}

// ---------------- k_scan: in-place exclusive prefix over the 32 chunk slots ----------------
__global__ __launch_bounds__(256) void k_scan(short* __restrict__ Chi, short* __restrict__ Clo) {
    int bn = blockIdx.y;
    int el = blockIdx.x * 1024 + threadIdx.x * 4;
    size_t off = (size_t)bn * 32 * 4096 + el;
    float run[4] = {0.f, 0.f, 0.f, 0.f};
    s16x4 h = *(const s16x4*)&Chi[off];
    s16x4 l = *(const s16x4*)&Clo[off];
    for (int cc = 0; cc < 31; ++cc) {
        s16x4 nh, nl;
        if (cc < 30) {
            nh = *(const s16x4*)&Chi[off + 4096];
            nl = *(const s16x4*)&Clo[off + 4096];
        }
        s16x4 oh, ol;
        #pragma unroll
        for (int r = 0; r < 4; ++r) {
            float o = bf2f(h[r]) + bf2f(l[r]);
            float cv = run[r];
            short hh = f2bf(cv);
            oh[r] = hh;
            ol[r] = f2bf(cv - bf2f(hh));
            run[r] = cv + o;
        }
        *(s16x4*)&Chi[off] = oh;
        *(s16x4*)&Clo[off] = ol;
        h = nh; l = nl;
        off += 4096;
    }
    s16x4 oh, ol;
    #pragma unroll
    for (int r = 0; r < 4; ++r) {
        short hh = f2bf(run[r]);
        oh[r] = hh;
        ol[r] = f2bf(run[r] - bf2f(hh));
    }
    *(s16x4*)&Chi[off] = oh;
    *(s16x4*)&Clo[off] = ol;
}

// ---------------- k_chunk: nudged_c = causal_intra(QM_c,P_c) + QM_c @ (Chi+Clo) ----------------
__global__ __launch_bounds__(256) void k_chunk(const short* __restrict__ pjqm,
                                               const short* __restrict__ Chi, const short* __restrict__ Clo,
                                               short* __restrict__ Nd) {
    int cc = blockIdx.x, n = blockIdx.y, b = blockIdx.z;
    int t = threadIdx.x, wave = t >> 6, lane = t & 63;
    int q = lane >> 4, c = lane & 15;
    __shared__ short Ps[64 * 72];     // P_c   [v][k]
    __shared__ short Pt_s[64 * 72];   // P_c^T [k][v]
    __shared__ short Ch[64 * 72];     // C_hi  [j][k]
    __shared__ short Cl[64 * 72];     // C_lo  [j][k]
    __shared__ short St[4][16 * 72];  // per-wave S strip [w][v]
    int w0g = b * W_ + cc * 64;

    const short* qmrow = &pjqm[(size_t)(w0g + wave * 16 + c) * 2048 + 1024 + n * KH];
    short8 bq0 = *(const short8*)(qmrow + q * 8);
    short8 bq1 = *(const short8*)(qmrow + 32 + q * 8);

    #pragma unroll
    for (int e = 0; e < 2; ++e) {
        int chv = e * 256 + t, row = chv >> 3, sub = chv & 7;
        short8 p8 = *(const short8*)&pjqm[(size_t)(w0g + row) * 2048 + n * KH + sub * 8];
        *(short8*)&Ps[row * 72 + sub * 8] = p8;
        #pragma unroll
        for (int j = 0; j < 8; ++j) Pt_s[(sub * 8 + j) * 72 + row] = p8[j];
        size_t cbase = ((size_t)((b * NH + n) * 32 + cc)) * 4096;
        *(short8*)&Ch[row * 72 + sub * 8] = *(const short8*)&Chi[cbase + row * 64 + sub * 8];
        *(short8*)&Cl[row * 72 + sub * 8] = *(const short8*)&Clo[cbase + row * 64 + sub * 8];
    }
    __syncthreads();
    #pragma unroll
    for (int ct = 0; ct < 4; ++ct) {
        short8 a0 = *(const short8*)&Ps[(ct * 16 + c) * 72 + q * 8];
        short8 a1 = *(const short8*)&Ps[(ct * 16 + c) * 72 + 32 + q * 8];
        f32x4 s = {};
        s = MFMA(a0, bq0, s);
        s = MFMA(a1, bq1, s);
        int vb = ct * 16 + q * 4, wl = wave * 16 + c;
        s16x4 pk;
        #pragma unroll
        for (int r = 0; r < 4; ++r) {
            float v = s[r];
            if (vb + r > wl) v = 0.f;
            pk[r] = f2bf(v);
        }
        *(s16x4*)&St[wave][c * 72 + ct * 16 + q * 4] = pk;
    }
    __syncthreads();
    f32x4 oc[4] = {};
    short8 as0 = *(const short8*)&St[wave][c * 72 + q * 8];
    short8 as1 = *(const short8*)&St[wave][c * 72 + 32 + q * 8];
    #pragma unroll
    for (int tj = 0; tj < 4; ++tj) {
        short8 bp0 = *(const short8*)&Pt_s[(tj * 16 + c) * 72 + q * 8];
        short8 bp1 = *(const short8*)&Pt_s[(tj * 16 + c) * 72 + 32 + q * 8];
        oc[tj] = MFMA(as0, bp0, oc[tj]);
        oc[tj] = MFMA(as1, bp1, oc[tj]);
        short8 bh0 = *(const short8*)&Ch[(tj * 16 + c) * 72 + q * 8];
        short8 bh1 = *(const short8*)&Ch[(tj * 16 + c) * 72 + 32 + q * 8];
        oc[tj] = MFMA(bq0, bh0, oc[tj]);
        oc[tj] = MFMA(bq1, bh1, oc[tj]);
        short8 bl0 = *(const short8*)&Cl[(tj * 16 + c) * 72 + q * 8];
        short8 bl1 = *(const short8*)&Cl[(tj * 16 + c) * 72 + 32 + q * 8];
        oc[tj] = MFMA(bq0, bl0, oc[tj]);
        oc[tj] = MFMA(bq1, bl1, oc[tj]);
    }
    #pragma unroll
    for (int tj = 0; tj < 4; ++tj)
        #pragma unroll
        for (int r = 0; r < 4; ++r)
            Nd[(size_t)(w0g + wave * 16 + q * 4 + r) * C_ + n * KH + tj * 16 + c] = f2bf(oc[tj][r]);
}

extern "C" void kernel_launch(void* const* d_in, const int* in_sizes, int n_in,
                              void* d_out, int out_size, void* d_ws, size_t ws_size,
                              hipStream_t stream) {
    const float* x  = (const float*)d_in[0];
    const float* Wp = (const float*)d_in[1];
    const float* Pm = (const float*)d_in[2];
    const float* Tr = (const float*)d_in[3];
    const float* Wm = (const float*)d_in[4];
    float* out = (float*)d_out;
    char* ws = (char*)d_ws;

    const size_t MB = 1024 * 1024;
    float* metric = (float*)ws;                        // 256 KB (fp32, consumed by k_outer)
    short* wp16  = (short*)(ws + 256 * 1024);          // 2 MB
    short* wf16  = (short*)(ws + 256 * 1024 + 4 * MB); // 2 MB
    short* x16   = (short*)(ws + 256 * 1024 + 6 * MB); // 16 MB (aliased by nd16 later)
    short* pjqm  = (short*)(ws + 256 * 1024 + 22 * MB);// 32 MB: [8192][2048] = [proj | qm]
    short* nd16  = x16;                                // x16 dead after GEMM1
    short* Chi   = (short*)d_out;                      // d_out as scratch: 16.75 MB
    short* Clo   = Chi + 8 * MB;                       // 16.75 MB (exactly fills d_out)

    k_prep<<<dim3(9488), dim3(256), 0, stream>>>(x, Wp, Pm, Tr, Wm, x16, wp16, wf16, metric);
    // proj into pjqm left half (OC=1024, row stride 2048), 128x64 tiles -> 4 blocks/CU
    k_gemm<1024, 2048, false><<<dim3(16, 64), dim3(256), 0, stream>>>(x16, wp16, (void*)pjqm);
    // O outer-products + fused qm (qm = proj @ M/8 into pjqm right half)
    k_outer<<<dim3(32, NH, B_), dim3(256), 0, stream>>>(pjqm, metric, Chi, Clo);
    k_scan<<<dim3(4, 64), dim3(256), 0, stream>>>(Chi, Clo);
    k_chunk<<<dim3(32, NH, B_), dim3(256), 0, stream>>>(pjqm, Chi, Clo, nd16);
    k_gemm<1024, 1024, true><<<dim3(16, 64), dim3(256), 0, stream>>>(nd16, wf16, (void*)out);
}

// Round 9
// 202.092 us; speedup vs baseline: 1.2238x; 1.0406x over previous
//
#include <hip/hip_runtime.h>

#define B_ 4
#define W_ 2048
#define C_ 1024
#define NH 16
#define KH 64

typedef __attribute__((ext_vector_type(8))) short short8;
typedef __attribute__((ext_vector_type(4))) short s16x4;
typedef __attribute__((ext_vector_type(4))) float f32x4;

__device__ __forceinline__ short f2bf(float f) {
    unsigned u = __builtin_bit_cast(unsigned, f);
    u = (u + 0x7FFFu + ((u >> 16) & 1u)) >> 16;
    return (short)u;
}
__device__ __forceinline__ float bf2f(short h) {
    return __builtin_bit_cast(float, ((unsigned)(unsigned short)h) << 16);
}

#define MFMA(a, b, cc) __builtin_amdgcn_mfma_f32_16x16x32_bf16(a, b, cc, 0, 0, 0)

// ---------------- k_prep: fused {cvt x, cvt Wp, Wf build, metric} ----------------
// ROUND-8 FIX: cvt branches were 1 float4/thread over 9216 tiny blocks -> ~1 outstanding
// load/wave, ~1 TB/s (12% peak), 43-48 us. Now 8 unrolled float4/thread over 1152 blocks
// (8 loads in flight/wave). Grid 1424 total:
//   [0,1024)    : x fp32 -> bf16   (2048 float4/block, 8/thread)
//   [1024,1152) : Wp fp32 -> bf16  (2048 float4/block, 8/thread)
//   [1152,1408) : Wf[o][n*64+k] = sum_j T[n][k][j] * Wm[o][n*64+j]
//   [1408,1424) : metric[n] = P[n] @ P[n]^T  (fp32, consumed by k_outer)
__global__ __launch_bounds__(256) void k_prep(const float* __restrict__ x, const float* __restrict__ Wp,
                                              const float* __restrict__ Pm, const float* __restrict__ Tr,
                                              const float* __restrict__ Wm,
                                              short* __restrict__ x16, short* __restrict__ wp16,
                                              short* __restrict__ wf16, float* __restrict__ metric) {
    int bid = blockIdx.x, t = threadIdx.x;
    __shared__ float sA[KH * 65];
    __shared__ float sB[KH * KH];
    if (bid < 1152) {
        const float4* src;
        short4* dst;
        int base;
        if (bid < 1024) { src = (const float4*)x;  dst = (short4*)x16;  base = bid * 2048 + t; }
        else            { src = (const float4*)Wp; dst = (short4*)wp16; base = (bid - 1024) * 2048 + t; }
        float4 v[8];
        #pragma unroll
        for (int e = 0; e < 8; ++e) v[e] = src[base + e * 256];
        #pragma unroll
        for (int e = 0; e < 8; ++e) {
            short4 o;
            o.x = f2bf(v[e].x); o.y = f2bf(v[e].y); o.z = f2bf(v[e].z); o.w = f2bf(v[e].w);
            dst[base + e * 256] = o;
        }
    } else if (bid < 1408) {
        int idx = bid - 1152;
        int oseg = idx & 15, n = idx >> 4;
        for (int i = t; i < KH * KH; i += 256) {
            sA[(i & 63) * 65 + (i >> 6)] = Tr[n * KH * KH + i];   // T^T
            int r = i >> 6, c = i & 63;
            sB[i] = Wm[(oseg * KH + r) * C_ + n * KH + c];
        }
        __syncthreads();
        for (int e = t; e < KH * KH; e += 256) {
            int r = e >> 6, k = e & 63;
            float s = 0.f;
            #pragma unroll 8
            for (int j = 0; j < KH; ++j) s += sA[j * 65 + k] * sB[r * KH + j];
            wf16[(oseg * KH + r) * C_ + n * KH + k] = f2bf(s);
        }
    } else {
        int n = bid - 1408;
        const float* Pn = Pm + n * KH * KH;
        for (int i = t; i < KH * KH; i += 256) {
            float v = Pn[i];
            sB[i] = v;
            sA[(i & 63) * 65 + (i >> 6)] = v;                      // P^T
        }
        __syncthreads();
        float* Mn = metric + n * KH * KH;
        for (int e = t; e < KH * KH; e += 256) {
            int i = e >> 6, k = e & 63;
            float s = 0.f;
            #pragma unroll 8
            for (int j = 0; j < KH; ++j) s += sB[i * KH + j] * sA[j * 65 + k];
            Mn[e] = s;
        }
    }
}

// ---------------- 128x64-tile m97-style GEMM: Out[M][col] = A[M][1024] @ Bw[col][1024]^T --------
// BN=64 -> grid (OC/64, 64) = 1024 blocks = 4 blocks/CU. STRIDE = Out row stride.
template <int OC, int STRIDE, bool OUT_FP32>
__global__ __launch_bounds__(256) void k_gemm(const short* __restrict__ A, const short* __restrict__ Bw,
                                              void* __restrict__ Out) {
    __shared__ short As[128 * 64];
    __shared__ short Bs[64 * 64];
    constexpr int NBX = OC / 64;
    int id = blockIdx.x + blockIdx.y * NBX;
    int fl = (id & 7) * (NBX * 64 / 8) + (id >> 3);   // bijective XCD swizzle (grid %8==0)
    int bm = fl / NBX, bn = fl % NBX;
    int t = threadIdx.x;
    int wave = t >> 6, lane = t & 63;
    int q = lane >> 4, c = lane & 15;
    int wy = wave >> 1, wx = wave & 1;                 // wave tile: 64 rows x 32 cols
    f32x4 acc[4][2] = {};
    int xsw = (c & 7);
    for (int k0 = 0; k0 < C_; k0 += 64) {
        __syncthreads();
        #pragma unroll
        for (int e = 0; e < 4; ++e) {
            int row = (e * 256 + t) >> 3;
            int ks = ((t & 7) ^ (row & 7)) * 8;
            __builtin_amdgcn_global_load_lds(
                (const __attribute__((address_space(1))) void*)&A[(size_t)(bm * 128 + row) * C_ + k0 + ks],
                (__attribute__((address_space(3))) void*)&As[e * 2048 + wave * 512], 16, 0, 0);
        }
        #pragma unroll
        for (int e = 0; e < 2; ++e) {
            int row = (e * 256 + t) >> 3;
            int ks = ((t & 7) ^ (row & 7)) * 8;
            __builtin_amdgcn_global_load_lds(
                (const __attribute__((address_space(1))) void*)&Bw[(size_t)(bn * 64 + row) * C_ + k0 + ks],
                (__attribute__((address_space(3))) void*)&Bs[e * 2048 + wave * 512], 16, 0, 0);
        }
        __syncthreads();
        #pragma unroll
        for (int kk = 0; kk < 64; kk += 32) {
            int o = kk >> 3;
            int xo = ((o + q) ^ xsw) * 8;
            short8 af[4], bfr[2];
            #pragma unroll
            for (int i = 0; i < 4; ++i)
                af[i] = *(const short8*)&As[(wy * 64 + i * 16 + c) * 64 + xo];
            #pragma unroll
            for (int j = 0; j < 2; ++j)
                bfr[j] = *(const short8*)&Bs[(wx * 32 + j * 16 + c) * 64 + xo];
            #pragma unroll
            for (int i = 0; i < 4; ++i)
                #pragma unroll
                for (int j = 0; j < 2; ++j)
                    acc[i][j] = MFMA(af[i], bfr[j], acc[i][j]);
        }
    }
    #pragma unroll
    for (int i = 0; i < 4; ++i)
        #pragma unroll
        for (int j = 0; j < 2; ++j)
            #pragma unroll
            for (int r = 0; r < 4; ++r) {
                int row = bm * 128 + wy * 64 + i * 16 + q * 4 + r;
                int col = bn * 64 + wx * 32 + j * 16 + c;
                if (OUT_FP32) ((float*)Out)[(size_t)row * STRIDE + col] = acc[i][j][r];
                else ((short*)Out)[(size_t)row * STRIDE + col] = f2bf(acc[i][j][r]);
            }
}

// ---------------- k_outer (fused qm): per (b,n,cc 64-row chunk) ----------------
// Always: qm[w][n*64+j] = sum_k proj[w][n*64+k] * (0.125*M_n)[j][k]  (K=64 MFMA, 8/wave)
// cc<31 : O_cc = P_cc^T @ P_cc -> bf16 hi/lo into Chi/Clo slot        (8 MFMA/wave)
__global__ __launch_bounds__(256) void k_outer(short* __restrict__ pjqm,
                                               const float* __restrict__ metric,
                                               short* __restrict__ Chi, short* __restrict__ Clo) {
    int cc = blockIdx.x, n = blockIdx.y, b = blockIdx.z;
    int bn = b * NH + n;
    int t = threadIdx.x, wave = t >> 6, lane = t & 63;
    int q = lane >> 4, c = lane & 15;
    int w0g = b * W_ + cc * 64;
    __shared__ short Pt_s[64 * 72];   // P_cc^T [k][v]
    __shared__ short Mb[64 * 72];     // 0.125 * M_n, [j][k]

    const float* Mn = metric + n * 4096;
    #pragma unroll
    for (int e = 0; e < 4; ++e) {
        int i4 = e * 256 + t;
        float4 v = ((const float4*)Mn)[i4];
        s16x4 o;
        o[0] = f2bf(v.x * 0.125f); o[1] = f2bf(v.y * 0.125f);
        o[2] = f2bf(v.z * 0.125f); o[3] = f2bf(v.w * 0.125f);
        int row = i4 >> 4, col = (i4 & 15) * 4;
        *(s16x4*)&Mb[row * 72 + col] = o;
    }
    if (cc < 31) {
        #pragma unroll
        for (int e = 0; e < 2; ++e) {
            int chv = e * 256 + t, row = chv >> 3, sub = chv & 7;
            short8 p8 = *(const short8*)&pjqm[(size_t)(w0g + row) * 2048 + n * KH + sub * 8];
            #pragma unroll
            for (int j = 0; j < 8; ++j) Pt_s[(sub * 8 + j) * 72 + row] = p8[j];
        }
    }
    __syncthreads();

    // qm: each wave handles its 16 rows (A-frags straight from global, L2-hot)
    {
        const short* arow = &pjqm[(size_t)(w0g + wave * 16 + c) * 2048 + n * KH];
        short8 a0 = *(const short8*)(arow + q * 8);
        short8 a1 = *(const short8*)(arow + 32 + q * 8);
        #pragma unroll
        for (int ct = 0; ct < 4; ++ct) {
            short8 b0 = *(const short8*)&Mb[(ct * 16 + c) * 72 + q * 8];
            short8 b1 = *(const short8*)&Mb[(ct * 16 + c) * 72 + 32 + q * 8];
            f32x4 acc = {};
            acc = MFMA(a0, b0, acc);
            acc = MFMA(a1, b1, acc);
            #pragma unroll
            for (int r = 0; r < 4; ++r)
                pjqm[(size_t)(w0g + wave * 16 + q * 4 + r) * 2048 + 1024 + n * KH + ct * 16 + c] =
                    f2bf(acc[r]);
        }
    }

    if (cc < 31) {
        short8 a0 = *(const short8*)&Pt_s[(wave * 16 + c) * 72 + q * 8];
        short8 a1 = *(const short8*)&Pt_s[(wave * 16 + c) * 72 + 32 + q * 8];
        size_t cbase = ((size_t)bn * 32 + cc) * 4096;
        #pragma unroll
        for (int tj = 0; tj < 4; ++tj) {
            short8 b0 = *(const short8*)&Pt_s[(tj * 16 + c) * 72 + q * 8];
            short8 b1 = *(const short8*)&Pt_s[(tj * 16 + c) * 72 + 32 + q * 8];
            f32x4 acc = {};
            acc = MFMA(a0, b0, acc);
            acc = MFMA(a1, b1, acc);
            s16x4 hi, lo;
            #pragma unroll
            for (int r = 0; r < 4; ++r) {
                float a = acc[r];
                short h = f2bf(a);
                hi[r] = h;
                lo[r] = f2bf(a - bf2f(h));
            }
            size_t off = cbase + (size_t)(tj * 16 + c) * 64 + wave * 16 + q * 4;  // [j][k], sym
            *(s16x4*)&Chi[off] = hi;
            *(s16x4*)&Clo[off] = lo;
        }
    }
}

// ---------------- k_scan: in-place exclusive prefix over the 32 chunk slots ----------------
__global__ __launch_bounds__(256) void k_scan(short* __restrict__ Chi, short* __restrict__ Clo) {
    int bn = blockIdx.y;
    int el = blockIdx.x * 1024 + threadIdx.x * 4;
    size_t off = (size_t)bn * 32 * 4096 + el;
    float run[4] = {0.f, 0.f, 0.f, 0.f};
    s16x4 h = *(const s16x4*)&Chi[off];
    s16x4 l = *(const s16x4*)&Clo[off];
    for (int cc = 0; cc < 31; ++cc) {
        s16x4 nh, nl;
        if (cc < 30) {
            nh = *(const s16x4*)&Chi[off + 4096];
            nl = *(const s16x4*)&Clo[off + 4096];
        }
        s16x4 oh, ol;
        #pragma unroll
        for (int r = 0; r < 4; ++r) {
            float o = bf2f(h[r]) + bf2f(l[r]);
            float cv = run[r];
            short hh = f2bf(cv);
            oh[r] = hh;
            ol[r] = f2bf(cv - bf2f(hh));
            run[r] = cv + o;
        }
        *(s16x4*)&Chi[off] = oh;
        *(s16x4*)&Clo[off] = ol;
        h = nh; l = nl;
        off += 4096;
    }
    s16x4 oh, ol;
    #pragma unroll
    for (int r = 0; r < 4; ++r) {
        short hh = f2bf(run[r]);
        oh[r] = hh;
        ol[r] = f2bf(run[r] - bf2f(hh));
    }
    *(s16x4*)&Chi[off] = oh;
    *(s16x4*)&Clo[off] = ol;
}

// ---------------- k_chunk: nudged_c = causal_intra(QM_c,P_c) + QM_c @ (Chi+Clo) ----------------
__global__ __launch_bounds__(256) void k_chunk(const short* __restrict__ pjqm,
                                               const short* __restrict__ Chi, const short* __restrict__ Clo,
                                               short* __restrict__ Nd) {
    int cc = blockIdx.x, n = blockIdx.y, b = blockIdx.z;
    int t = threadIdx.x, wave = t >> 6, lane = t & 63;
    int q = lane >> 4, c = lane & 15;
    __shared__ short Ps[64 * 72];     // P_c   [v][k]
    __shared__ short Pt_s[64 * 72];   // P_c^T [k][v]
    __shared__ short Ch[64 * 72];     // C_hi  [j][k]
    __shared__ short Cl[64 * 72];     // C_lo  [j][k]
    __shared__ short St[4][16 * 72];  // per-wave S strip [w][v]
    int w0g = b * W_ + cc * 64;

    const short* qmrow = &pjqm[(size_t)(w0g + wave * 16 + c) * 2048 + 1024 + n * KH];
    short8 bq0 = *(const short8*)(qmrow + q * 8);
    short8 bq1 = *(const short8*)(qmrow + 32 + q * 8);

    #pragma unroll
    for (int e = 0; e < 2; ++e) {
        int chv = e * 256 + t, row = chv >> 3, sub = chv & 7;
        short8 p8 = *(const short8*)&pjqm[(size_t)(w0g + row) * 2048 + n * KH + sub * 8];
        *(short8*)&Ps[row * 72 + sub * 8] = p8;
        #pragma unroll
        for (int j = 0; j < 8; ++j) Pt_s[(sub * 8 + j) * 72 + row] = p8[j];
        size_t cbase = ((size_t)((b * NH + n) * 32 + cc)) * 4096;
        *(short8*)&Ch[row * 72 + sub * 8] = *(const short8*)&Chi[cbase + row * 64 + sub * 8];
        *(short8*)&Cl[row * 72 + sub * 8] = *(const short8*)&Clo[cbase + row * 64 + sub * 8];
    }
    __syncthreads();
    #pragma unroll
    for (int ct = 0; ct < 4; ++ct) {
        short8 a0 = *(const short8*)&Ps[(ct * 16 + c) * 72 + q * 8];
        short8 a1 = *(const short8*)&Ps[(ct * 16 + c) * 72 + 32 + q * 8];
        f32x4 s = {};
        s = MFMA(a0, bq0, s);
        s = MFMA(a1, bq1, s);
        int vb = ct * 16 + q * 4, wl = wave * 16 + c;
        s16x4 pk;
        #pragma unroll
        for (int r = 0; r < 4; ++r) {
            float v = s[r];
            if (vb + r > wl) v = 0.f;
            pk[r] = f2bf(v);
        }
        *(s16x4*)&St[wave][c * 72 + ct * 16 + q * 4] = pk;
    }
    __syncthreads();
    f32x4 oc[4] = {};
    short8 as0 = *(const short8*)&St[wave][c * 72 + q * 8];
    short8 as1 = *(const short8*)&St[wave][c * 72 + 32 + q * 8];
    #pragma unroll
    for (int tj = 0; tj < 4; ++tj) {
        short8 bp0 = *(const short8*)&Pt_s[(tj * 16 + c) * 72 + q * 8];
        short8 bp1 = *(const short8*)&Pt_s[(tj * 16 + c) * 72 + 32 + q * 8];
        oc[tj] = MFMA(as0, bp0, oc[tj]);
        oc[tj] = MFMA(as1, bp1, oc[tj]);
        short8 bh0 = *(const short8*)&Ch[(tj * 16 + c) * 72 + q * 8];
        short8 bh1 = *(const short8*)&Ch[(tj * 16 + c) * 72 + 32 + q * 8];
        oc[tj] = MFMA(bq0, bh0, oc[tj]);
        oc[tj] = MFMA(bq1, bh1, oc[tj]);
        short8 bl0 = *(const short8*)&Cl[(tj * 16 + c) * 72 + q * 8];
        short8 bl1 = *(const short8*)&Cl[(tj * 16 + c) * 72 + 32 + q * 8];
        oc[tj] = MFMA(bq0, bl0, oc[tj]);
        oc[tj] = MFMA(bq1, bl1, oc[tj]);
    }
    #pragma unroll
    for (int tj = 0; tj < 4; ++tj)
        #pragma unroll
        for (int r = 0; r < 4; ++r)
            Nd[(size_t)(w0g + wave * 16 + q * 4 + r) * C_ + n * KH + tj * 16 + c] = f2bf(oc[tj][r]);
}

extern "C" void kernel_launch(void* const* d_in, const int* in_sizes, int n_in,
                              void* d_out, int out_size, void* d_ws, size_t ws_size,
                              hipStream_t stream) {
    const float* x  = (const float*)d_in[0];
    const float* Wp = (const float*)d_in[1];
    const float* Pm = (const float*)d_in[2];
    const float* Tr = (const float*)d_in[3];
    const float* Wm = (const float*)d_in[4];
    float* out = (float*)d_out;
    char* ws = (char*)d_ws;

    const size_t MB = 1024 * 1024;
    float* metric = (float*)ws;                        // 256 KB (fp32, consumed by k_outer)
    short* wp16  = (short*)(ws + 256 * 1024);          // 2 MB
    short* wf16  = (short*)(ws + 256 * 1024 + 4 * MB); // 2 MB
    short* x16   = (short*)(ws + 256 * 1024 + 6 * MB); // 16 MB (aliased by nd16 later)
    short* pjqm  = (short*)(ws + 256 * 1024 + 22 * MB);// 32 MB: [8192][2048] = [proj | qm]
    short* nd16  = x16;                                // x16 dead after GEMM1
    short* Chi   = (short*)d_out;                      // d_out as scratch: 16.75 MB
    short* Clo   = Chi + 8 * MB;                       // 16.75 MB (exactly fills d_out)

    k_prep<<<dim3(1424), dim3(256), 0, stream>>>(x, Wp, Pm, Tr, Wm, x16, wp16, wf16, metric);
    // proj into pjqm left half (OC=1024, row stride 2048), 128x64 tiles -> 4 blocks/CU
    k_gemm<1024, 2048, false><<<dim3(16, 64), dim3(256), 0, stream>>>(x16, wp16, (void*)pjqm);
    // O outer-products + fused qm (qm = proj @ M/8 into pjqm right half)
    k_outer<<<dim3(32, NH, B_), dim3(256), 0, stream>>>(pjqm, metric, Chi, Clo);
    k_scan<<<dim3(4, 64), dim3(256), 0, stream>>>(Chi, Clo);
    k_chunk<<<dim3(32, NH, B_), dim3(256), 0, stream>>>(pjqm, Chi, Clo, nd16);
    k_gemm<1024, 1024, true><<<dim3(16, 64), dim3(256), 0, stream>>>(nd16, wf16, (void*)out);
}